// Round 1
// baseline (159.548 us; speedup 1.0000x reference)
//
#include <hip/hip_runtime.h>
#include <cstdint>
#include <cstddef>

#define E_TOT 2048
#define A_TOT 512
#define FEAT  128
#define N_UP  1024
#define K_RBF 32
#define DIM   256

// ---------------------------------------------------------------------------
// Kernel 0: rbf(e,a) = mean_k exp(-(r-mu_k)^2 / softplus(sigma_k))
// ---------------------------------------------------------------------------
__global__ __launch_bounds__(256) void rbf_kernel(
    const float* __restrict__ r_im, const float* __restrict__ mu,
    const float* __restrict__ sigma, float* __restrict__ rbf_out) {
  __shared__ float s_mu[K_RBF];
  __shared__ float s_inv[K_RBF];
  int t = threadIdx.x;
  if (t < K_RBF) {
    s_mu[t] = mu[t];
    float s = sigma[t];
    float sp = (s > 20.0f) ? s : log1pf(__expf(s));  // softplus
    s_inv[t] = 1.0f / sp;
  }
  __syncthreads();
  int idx = blockIdx.x * 256 + t;
  if (idx < E_TOT * A_TOT) {
    float rv = r_im[idx];
    float acc = 0.0f;
#pragma unroll
    for (int k = 0; k < K_RBF; ++k) {
      float d = rv - s_mu[k];
      acc += __expf(-d * d * s_inv[k]);
    }
    rbf_out[idx] = acc * (1.0f / K_RBF);
  }
}

// ---------------------------------------------------------------------------
// Main pass: read h once; produce atom partials (sum over tile electrons) and
// elec partials (sum over tile atoms). Tile = EB electrons x AB atoms.
// 256 threads: r = t>>5 in [0,8), f4 = t&31 (float4 index into FEAT).
// ---------------------------------------------------------------------------
template <int EB, int AB>
__global__ __launch_bounds__(256) void main_pass(
    const float* __restrict__ h, const float* __restrict__ rbf,
    float* __restrict__ ws_atom,   // [E_TOT/EB][A_TOT][FEAT]
    float* __restrict__ ws_elec) { // [A_TOT/AB][E_TOT][FEAT]
  constexpr int GA = A_TOT / AB;
  constexpr int NIA = AB / 8;
  const int bid = blockIdx.x;
  const int g_a = bid % GA;
  const int g_e = bid / GA;
  const int e0 = g_e * EB;
  const int a0 = g_a * AB;
  const int t = threadIdx.x;
  const int r = t >> 5;
  const int f4 = t & 31;

  __shared__ float rbf_lds[EB * AB];
  __shared__ float4 red[4][32];

  for (int i = t; i < EB * AB; i += 256) {
    int e_l = i / AB, a_l = i % AB;
    rbf_lds[i] = rbf[(size_t)(e0 + e_l) * A_TOT + a0 + a_l];
  }
  __syncthreads();

  float4 atom_acc[NIA];
#pragma unroll
  for (int i = 0; i < NIA; ++i) atom_acc[i] = make_float4(0.f, 0.f, 0.f, 0.f);

  for (int e = 0; e < EB; ++e) {
    const float* hrow = h + ((size_t)(e0 + e) * A_TOT + a0) * FEAT;
    float4 esum = make_float4(0.f, 0.f, 0.f, 0.f);
#pragma unroll
    for (int ia = 0; ia < NIA; ++ia) {
      const int a_l = ia * 8 + r;
      float4 hv = *reinterpret_cast<const float4*>(hrow + (size_t)a_l * FEAT + f4 * 4);
      float rb = rbf_lds[e * AB + a_l];
      float4 v = make_float4(hv.x * rb, hv.y * rb, hv.z * rb, hv.w * rb);
      atom_acc[ia].x += v.x; atom_acc[ia].y += v.y;
      atom_acc[ia].z += v.z; atom_acc[ia].w += v.w;
      esum.x += v.x; esum.y += v.y; esum.z += v.z; esum.w += v.w;
    }
    // reduce esum over r (8 threads share each f4): pair-reduce within wave,
    // then 4-wave reduce through LDS.
    esum.x += __shfl_down(esum.x, 32, 64);
    esum.y += __shfl_down(esum.y, 32, 64);
    esum.z += __shfl_down(esum.z, 32, 64);
    esum.w += __shfl_down(esum.w, 32, 64);
    const int wave = t >> 6;
    const int lane = t & 63;
    if (lane < 32) red[wave][lane] = esum;
    __syncthreads();
    if (t < 32) {
      float4 s0 = red[0][t], s1 = red[1][t], s2 = red[2][t], s3 = red[3][t];
      float4 s = make_float4(s0.x + s1.x + s2.x + s3.x, s0.y + s1.y + s2.y + s3.y,
                             s0.z + s1.z + s2.z + s3.z, s0.w + s1.w + s2.w + s3.w);
      reinterpret_cast<float4*>(ws_elec)[((size_t)g_a * E_TOT + e0 + e) * 32 + t] = s;
    }
    __syncthreads();
  }

#pragma unroll
  for (int ia = 0; ia < NIA; ++ia) {
    const int a_l = ia * 8 + r;
    reinterpret_cast<float4*>(ws_atom)[((size_t)g_e * A_TOT + a0 + a_l) * 32 + f4] =
        atom_acc[ia];
  }
}

// ---------------------------------------------------------------------------
// atom_final: one block per atom. Reduce ge_total partials -> spin means,
// then 256-dot + tanh*gain. t<128: up (f=t), t>=128: dn (f=t-128).
// ---------------------------------------------------------------------------
__global__ __launch_bounds__(256) void atom_final(
    const float* __restrict__ ws_atom, const float* __restrict__ W,
    const float* __restrict__ b, float* __restrict__ out, int ge_total) {
  const int a = blockIdx.x;
  const int t = threadIdx.x;
  __shared__ float s_in[2 * FEAT];
  const int spin = t >> 7;
  const int f = t & 127;
  const int g0 = spin * (ge_total >> 1);
  float acc = 0.0f;
  for (int g = 0; g < (ge_total >> 1); ++g) {
    acc += ws_atom[((size_t)(g0 + g) * A_TOT + a) * FEAT + f];
  }
  s_in[t] = acc * (1.0f / (float)N_UP);
  __syncthreads();
  float o = b[t];
#pragma unroll 4
  for (int k = 0; k < 2 * FEAT; ++k) {
    o += s_in[k] * W[(size_t)k * DIM + t];
  }
  out[(size_t)a * DIM + t] = tanhf(o) * (5.0f / 3.0f);
}

// ---------------------------------------------------------------------------
// elec_final: sum ga_total partials, /A_TOT, write to out + 131072 floats.
// ---------------------------------------------------------------------------
__global__ __launch_bounds__(256) void elec_final(
    const float* __restrict__ ws_elec, float* __restrict__ out, int ga_total) {
  const int idx = blockIdx.x * 256 + threadIdx.x;  // float4 index, E_TOT*FEAT/4
  const int n4 = E_TOT * FEAT / 4;
  if (idx >= n4) return;
  const float4* in4 = reinterpret_cast<const float4*>(ws_elec);
  float4 s = make_float4(0.f, 0.f, 0.f, 0.f);
  for (int g = 0; g < ga_total; ++g) {
    float4 v = in4[(size_t)g * n4 + idx];
    s.x += v.x; s.y += v.y; s.z += v.z; s.w += v.w;
  }
  const float inv = 1.0f / (float)A_TOT;
  s.x *= inv; s.y *= inv; s.z *= inv; s.w *= inv;
  reinterpret_cast<float4*>(out + (size_t)A_TOT * DIM)[idx] = s;
}

// ---------------------------------------------------------------------------
extern "C" void kernel_launch(void* const* d_in, const int* in_sizes, int n_in,
                              void* d_out, int out_size, void* d_ws, size_t ws_size,
                              hipStream_t stream) {
  const float* h     = (const float*)d_in[0];  // (2048,512,128)
  const float* r_im  = (const float*)d_in[1];  // (2048,512)
  const float* mu    = (const float*)d_in[2];  // (32,)
  const float* sigma = (const float*)d_in[3];  // (32,)
  const float* W     = (const float*)d_in[4];  // (256,256)
  const float* b     = (const float*)d_in[5];  // (256,)
  float* out = (float*)d_out;

  float* ws_rbf = (float*)d_ws;                      // E_TOT*A_TOT floats (4 MB)
  float* ws_atom = ws_rbf + (size_t)E_TOT * A_TOT;   // GE*A_TOT*FEAT floats

  // rbf
  rbf_kernel<<<(E_TOT * A_TOT + 255) / 256, 256, 0, stream>>>(r_im, mu, sigma, ws_rbf);

  const size_t base = (size_t)E_TOT * A_TOT * 4;
  const size_t need32 = base + (size_t)(E_TOT / 32) * A_TOT * FEAT * 4
                             + (size_t)(A_TOT / 64) * E_TOT * FEAT * 4;   // ~28 MB
  const size_t need64 = base + (size_t)(E_TOT / 64) * A_TOT * FEAT * 4
                             + (size_t)(A_TOT / 128) * E_TOT * FEAT * 4;  // ~16 MB

  if (ws_size >= need32) {
    constexpr int GE = E_TOT / 32, GA = A_TOT / 64;  // 64, 8
    float* ws_elec = ws_atom + (size_t)GE * A_TOT * FEAT;
    main_pass<32, 64><<<GE * GA, 256, 0, stream>>>(h, ws_rbf, ws_atom, ws_elec);
    atom_final<<<A_TOT, 256, 0, stream>>>(ws_atom, W, b, out, GE);
    elec_final<<<(E_TOT * FEAT / 4 + 255) / 256, 256, 0, stream>>>(ws_elec, out, GA);
  } else {
    (void)need64;
    constexpr int GE = E_TOT / 64, GA = A_TOT / 128;  // 32, 4
    float* ws_elec = ws_atom + (size_t)GE * A_TOT * FEAT;
    main_pass<64, 128><<<GE * GA, 256, 0, stream>>>(h, ws_rbf, ws_atom, ws_elec);
    atom_final<<<A_TOT, 256, 0, stream>>>(ws_atom, W, b, out, GE);
    elec_final<<<(E_TOT * FEAT / 4 + 255) / 256, 256, 0, stream>>>(ws_elec, out, GA);
  }
}